// Round 1
// baseline (378.801 us; speedup 1.0000x reference)
//
#include <hip/hip_runtime.h>
#include <hip/hip_bf16.h>

#define NFEAT 50
#define EDIM 64
#define LN_EPS 1e-5f
#define NEG_INF_C (-1000000000.0f)
#define NB 4

typedef __bf16 bf16_t;
typedef __bf16 bf16x8 __attribute__((ext_vector_type(8)));
typedef __bf16 bf16x4 __attribute__((ext_vector_type(4)));
typedef float f32x4 __attribute__((ext_vector_type(4)));

// ws layout:
//   attnT: bf16 [T][64][64], attnT[t][g][f] = attn[t][f][g], zero padded
//   WT:    bf16 [T][2][64][64], WT[t][i][e][k] = w0[t][i*64+k][e]  (B-operand ready)
//   tbT:   f32  [T][64][64], tbT[t][e][f] = tb[t][f][e], zero padded (f>=50 -> 0)
//   gwT:   f32  [64][64],    gwT[e][f]    = gw[f][e],    zero padded
//   cst:   f32  [T],         cst[t] = sum_{f,e} tb[t][f][e]*gw[f][e]

__global__ __launch_bounds__(256) void prep_kernel(
    const float* __restrict__ masker, const float* __restrict__ ln_w,
    const float* __restrict__ ln_b, const float* __restrict__ tw,
    const float* __restrict__ tb, const float* __restrict__ gw,
    bf16_t* __restrict__ ws_attnT, bf16_t* __restrict__ ws_WT,
    float* __restrict__ ws_tbT, float* __restrict__ ws_gwT,
    float* __restrict__ ws_cst)
{
  __shared__ float red[2][4];
  const int tid = threadIdx.x;
  const int lane = tid & 63;
  const int gidx = blockIdx.x * 256 + tid;   // 0..4095

  // ---- WT staging: 16384 elems, 4/thread ----
#pragma unroll
  for (int j = 0; j < 4; ++j) {
    int o = gidx * 4 + j;            // ((t*2+i)*64 + e)*64 + k
    int k = o & 63;
    int e = (o >> 6) & 63;
    int ti = o >> 12;                // t*2+i
    ws_WT[o] = (bf16_t)tw[(ti * 64 + k) * 64 + e];
  }

  // ---- tbT staging: 8192 elems, 2/thread ----
#pragma unroll
  for (int j = 0; j < 2; ++j) {
    int o = gidx * 2 + j;            // (t*64 + e)*64 + f
    int f = o & 63;
    int e = (o >> 6) & 63;
    int t = o >> 12;
    ws_tbT[o] = (f < NFEAT) ? tb[(t * NFEAT + f) * EDIM + e] : 0.f;
  }

  // ---- gwT staging: 4096 elems, 1/thread ----
  {
    int o = gidx;                    // e*64 + f
    int f = o & 63;
    int e = o >> 6;
    ws_gwT[o] = (f < NFEAT) ? gw[f * EDIM + e] : 0.f;
  }

  // ---- gate-bias constants: cst[t] = sum tb_t * gw (block 0 only) ----
  if (blockIdx.x == 0) {
    float s0 = 0.f, s1 = 0.f;
    for (int i = tid; i < NFEAT * EDIM; i += 256) {
      float g = gw[i];
      s0 += tb[i] * g;
      s1 += tb[NFEAT * EDIM + i] * g;
    }
    for (int off = 32; off > 0; off >>= 1) {
      s0 += __shfl_xor(s0, off);
      s1 += __shfl_xor(s1, off);
    }
    if (lane == 0) { red[0][tid >> 6] = s0; red[1][tid >> 6] = s1; }
    __syncthreads();
    if (tid == 0) {
      ws_cst[0] = red[0][0] + red[0][1] + red[0][2] + red[0][3];
      ws_cst[1] = red[1][0] + red[1][1] + red[1][2] + red[1][3];
    }
  }

  // ---- attention columns: 128 tasks (t,g) over 64 waves, 2 each ----
  const int wg = blockIdx.x * 4 + (tid >> 6);  // 0..63
  const int f = lane;
  const bool fv = (f < NFEAT);
  for (int i = 0; i < 2; ++i) {
    int col = wg * 2 + i;            // 0..127
    int t = col >> 6, g = col & 63;
    float val = 0.f;
    if (fv && g < NFEAT) {
      float a0 = masker[((t * 3 + 0) * NFEAT + f) * NFEAT + g];
      float a1 = masker[((t * 3 + 1) * NFEAT + f) * NFEAT + g];
      float a2 = masker[((t * 3 + 2) * NFEAT + f) * NFEAT + g];
      float prod = a0 * a1 * a2;
      val = prod > 0.f ? prod : 0.f;            // relu
    }
    float s = val;
    for (int off = 32; off > 0; off >>= 1) s += __shfl_xor(s, off);
    float mean = s / (float)NFEAT;
    float d = fv ? (val - mean) : 0.f;
    float v2 = d * d;
    for (int off = 32; off > 0; off >>= 1) v2 += __shfl_xor(v2, off);
    float var = v2 / (float)NFEAT;
    float lw = fv ? ln_w[f] : 0.f;
    float lb = fv ? ln_b[f] : 0.f;
    float aln = d * rsqrtf(var + LN_EPS) * lw + lb;
    float logit = aln + ((val != 0.f) ? 0.f : NEG_INF_C) + ((f == g) ? 1.f : 0.f);
    if (!fv) logit = -3.0e38f;
    float mx = logit;
    for (int off = 32; off > 0; off >>= 1) mx = fmaxf(mx, __shfl_xor(mx, off));
    float ex = fv ? expf(logit - mx) : 0.f;
    float se = ex;
    for (int off = 32; off > 0; off >>= 1) se += __shfl_xor(se, off);
    float attn = (fv && g < NFEAT && val != 0.f) ? (ex / se) : 0.f;
    ws_attnT[(t * 64 + g) * 64 + f] = (bf16_t)attn;
  }
}

// One block = NB consecutive batches, 4 waves, wave w owns rows 16w..16w+15.
// VGPR diet: only feat frags + accumulators persist; attnT/tb/gw frags are
// per-batch transient reloads (L1/L2-hot). __launch_bounds__(256,4) forces
// <=128 VGPR -> 4 blocks/CU (was 160 -> 2 blocks/CU). Next batch's feat is
// prefetched into raw f32 regs so its HBM/L3 latency hides under pass1+pass2.
__global__ __launch_bounds__(256, 4) void main_kernel(
    const float* __restrict__ feat, const float* __restrict__ gb,
    const bf16_t* __restrict__ ws_attnT, const bf16_t* __restrict__ ws_WT,
    const float* __restrict__ ws_tbT, const float* __restrict__ ws_gwT,
    const float* __restrict__ ws_cst,
    float* __restrict__ out)
{
  __shared__ bf16_t sPT[2][64 * 72];   // P^T[e][f'] per t, pitch 72
  __shared__ float sLog[2][4];

  const int tid = threadIdx.x;
  const int w = tid >> 6;
  const int lane = tid & 63;
  const int l16 = lane & 15;
  const int lquad = lane >> 4;
  const int m0 = w * 16;

  const float gbv = gb[0];
  const float cst0 = ws_cst[0];
  const float cst1 = ws_cst[1];
  const int fA = m0 + l16;
  const bool fAv = (fA < NFEAT);
  const int b0 = blockIdx.x * NB;
  const int featoff = fA * 64 + lquad * 8;        // float offset within a batch

  // ---- prefetch feat for ib = 0 ----
  f32x4 raw[4];
  if (fAv) {
    const float* fb = feat + b0 * (NFEAT * EDIM) + featoff;
    raw[0] = *(const f32x4*)(fb);
    raw[1] = *(const f32x4*)(fb + 4);
    raw[2] = *(const f32x4*)(fb + 32);
    raw[3] = *(const f32x4*)(fb + 36);
  }

  for (int ib = 0; ib < NB; ++ib) {
    const int b = b0 + ib;

    // ---- convert prefetched raw -> bf16 A-frags ----
    bf16x8 a[2];
#pragma unroll
    for (int kc = 0; kc < 2; ++kc)
#pragma unroll
      for (int j = 0; j < 8; ++j) a[kc][j] = (bf16_t)0.f;
    if (fAv) {
#pragma unroll
      for (int kc = 0; kc < 2; ++kc)
#pragma unroll
        for (int j = 0; j < 4; ++j) {
          a[kc][j]     = (bf16_t)raw[kc * 2][j];
          a[kc][j + 4] = (bf16_t)raw[kc * 2 + 1][j];
        }
    }

    // ---- issue prefetch for next batch (overlaps pass1+pass2) ----
    if (ib + 1 < NB && fAv) {
      const float* fb = feat + (b + 1) * (NFEAT * EDIM) + featoff;
      raw[0] = *(const f32x4*)(fb);
      raw[1] = *(const f32x4*)(fb + 4);
      raw[2] = *(const f32x4*)(fb + 32);
      raw[3] = *(const f32x4*)(fb + 36);
    }

    f32x4 accH[2][4], accP[2][4];
#pragma unroll
    for (int t = 0; t < 2; ++t)
#pragma unroll
      for (int n = 0; n < 4; ++n) {
        accH[t][n] = (f32x4){0.f, 0.f, 0.f, 0.f};
        accP[t][n] = (f32x4){0.f, 0.f, 0.f, 0.f};
      }

    // ---- pass 1: accH[t] = F@W1_t, accP[t] = F@W2_t ----
#pragma unroll
    for (int kc = 0; kc < 2; ++kc) {
#pragma unroll
      for (int n = 0; n < 4; ++n) {
        const int bo = (n * 16 + l16) * 64 + kc * 32 + lquad * 8;
        const bf16x8 b10 = *(const bf16x8*)(ws_WT + (0 * 64) * 64 + bo);  // t0 W1
        const bf16x8 b20 = *(const bf16x8*)(ws_WT + (1 * 64) * 64 + bo);  // t0 W2
        const bf16x8 b11 = *(const bf16x8*)(ws_WT + (2 * 64) * 64 + bo);  // t1 W1
        const bf16x8 b21 = *(const bf16x8*)(ws_WT + (3 * 64) * 64 + bo);  // t1 W2
        accH[0][n] = __builtin_amdgcn_mfma_f32_16x16x32_bf16(a[kc], b10, accH[0][n], 0, 0, 0);
        accP[0][n] = __builtin_amdgcn_mfma_f32_16x16x32_bf16(a[kc], b20, accP[0][n], 0, 0, 0);
        accH[1][n] = __builtin_amdgcn_mfma_f32_16x16x32_bf16(a[kc], b11, accH[1][n], 0, 0, 0);
        accP[1][n] = __builtin_amdgcn_mfma_f32_16x16x32_bf16(a[kc], b21, accP[1][n], 0, 0, 0);
      }
    }

    // ---- write both P^T tiles to LDS ----
#pragma unroll
    for (int t = 0; t < 2; ++t)
#pragma unroll
      for (int n = 0; n < 4; ++n) {
        bf16x4 pv;
        pv[0] = (bf16_t)accP[t][n][0]; pv[1] = (bf16_t)accP[t][n][1];
        pv[2] = (bf16_t)accP[t][n][2]; pv[3] = (bf16_t)accP[t][n][3];
        *(bf16x4*)&sPT[t][(n * 16 + l16) * 72 + m0 + lquad * 4] = pv;
      }
    __syncthreads();

    // ---- pass 2: accH[t] += attnT_t @ P_t (attnT frags reloaded, L1-hot) ----
#pragma unroll
    for (int kc = 0; kc < 2; ++kc) {
      const bf16x8 aat0 = *(const bf16x8*)(ws_attnT + (0 * 64 + m0 + l16) * 64 + kc * 32 + lquad * 8);
      const bf16x8 aat1 = *(const bf16x8*)(ws_attnT + (1 * 64 + m0 + l16) * 64 + kc * 32 + lquad * 8);
#pragma unroll
      for (int n = 0; n < 4; ++n) {
        const int so = (n * 16 + l16) * 72 + kc * 32 + lquad * 8;
        const bf16x8 bp0 = *(const bf16x8*)(&sPT[0][so]);
        const bf16x8 bp1 = *(const bf16x8*)(&sPT[1][so]);
        accH[0][n] = __builtin_amdgcn_mfma_f32_16x16x32_bf16(aat0, bp0, accH[0][n], 0, 0, 0);
        accH[1][n] = __builtin_amdgcn_mfma_f32_16x16x32_bf16(aat1, bp1, accH[1][n], 0, 0, 0);
      }
    }

    // ---- gate-logit partials: p_t = sum accH_t * gw (bias folded into cst) ----
    f32x4 gwv[4];
#pragma unroll
    for (int n = 0; n < 4; ++n)
      gwv[n] = *(const f32x4*)(ws_gwT + (n * 16 + l16) * 64 + m0 + lquad * 4);

    float p0 = 0.f, p1 = 0.f;
#pragma unroll
    for (int n = 0; n < 4; ++n)
#pragma unroll
      for (int r = 0; r < 4; ++r) {
        p0 += accH[0][n][r] * gwv[n][r];
        p1 += accH[1][n][r] * gwv[n][r];
      }
#pragma unroll
    for (int off = 32; off > 0; off >>= 1) {
      p0 += __shfl_xor(p0, off);
      p1 += __shfl_xor(p1, off);
    }
    if (lane == 0) { sLog[0][w] = p0; sLog[1][w] = p1; }
    __syncthreads();   // sLog visible; also fences sPT reads before next iter's writes

    // ---- transient bias frags (consumed at store) ----
    f32x4 tbv0[4], tbv1[4];
#pragma unroll
    for (int n = 0; n < 4; ++n) {
      const int ro = (n * 16 + l16) * 64 + m0 + lquad * 4;
      tbv0[n] = *(const f32x4*)(ws_tbT + ro);
      tbv1[n] = *(const f32x4*)(ws_tbT + 64 * 64 + ro);
    }

    // ---- gate softmax over T=2, weighted sum, store ----
    const float g0 = sLog[0][0] + sLog[0][1] + sLog[0][2] + sLog[0][3] + cst0 + gbv;
    const float g1 = sLog[1][0] + sLog[1][1] + sLog[1][2] + sLog[1][3] + cst1 + gbv;
    const float mx = fmaxf(g0, g1);
    const float e0 = expf(g0 - mx), e1 = expf(g1 - mx);
    const float inv = 1.f / (e0 + e1);
    const float ga0 = e0 * inv, ga1 = e1 * inv;

    float* outb = out + b * (NFEAT * EDIM);
#pragma unroll
    for (int n = 0; n < 4; ++n) {
      int e = n * 16 + l16;
#pragma unroll
      for (int r = 0; r < 4; ++r) {
        int f = m0 + lquad * 4 + r;
        if (f < NFEAT)
          outb[f * 64 + e] = ga0 * (accH[0][n][r] + tbv0[n][r])
                           + ga1 * (accH[1][n][r] + tbv1[n][r]);
      }
    }
  }
}

extern "C" void kernel_launch(void* const* d_in, const int* in_sizes, int n_in,
                              void* d_out, int out_size, void* d_ws, size_t ws_size,
                              hipStream_t stream) {
  const float* feat   = (const float*)d_in[0];
  const float* masker = (const float*)d_in[1];
  const float* tw     = (const float*)d_in[2];
  const float* tb     = (const float*)d_in[3];
  const float* lnw    = (const float*)d_in[4];
  const float* lnb    = (const float*)d_in[5];
  const float* gw     = (const float*)d_in[6];
  const float* gb     = (const float*)d_in[7];
  float* out = (float*)d_out;

  bf16_t* ws_attnT = (bf16_t*)d_ws;                 // 8192 bf16
  bf16_t* ws_WT    = ws_attnT + 2 * 64 * 64;        // 16384 bf16
  float*  ws_tbT   = (float*)(ws_WT + 4 * 64 * 64); // 8192 f32
  float*  ws_gwT   = ws_tbT + 2 * 64 * 64;          // 4096 f32
  float*  ws_cst   = ws_gwT + 64 * 64;              // 2 f32

  prep_kernel<<<16, 256, 0, stream>>>(masker, lnw, lnb, tw, tb, gw,
                                      ws_attnT, ws_WT, ws_tbT, ws_gwT, ws_cst);
  main_kernel<<<4096 / NB, 256, 0, stream>>>(feat, gb, ws_attnT, ws_WT,
                                             ws_tbT, ws_gwT, ws_cst, out);
}

// Round 2
// 213.023 us; speedup vs baseline: 1.7782x; 1.7782x over previous
//
#include <hip/hip_runtime.h>
#include <hip/hip_bf16.h>

#define NFEAT 50
#define EDIM 64
#define LN_EPS 1e-5f
#define NEG_INF_C (-1000000000.0f)

typedef __bf16 bf16_t;
typedef __bf16 bf16x8 __attribute__((ext_vector_type(8)));
typedef __bf16 bf16x4 __attribute__((ext_vector_type(4)));
typedef float f32x4 __attribute__((ext_vector_type(4)));

// ws layout:
//   attnT: bf16 [T][64][64], attnT[t][g][f] = attn[t][f][g], zero padded
//   WT:    bf16 [T][2][64][64], WT[t][i][e][k] = w0[t][i*64+k][e]  (B-operand ready)
//   tbT:   f32  [T][64][64], tbT[t][e][f] = tb[t][f][e], zero padded (f>=50 -> 0)
//   gwT:   f32  [64][64],    gwT[e][f]    = gw[f][e],    zero padded
//   cst:   f32  [T],         cst[t] = sum_{f,e} tb[t][f][e]*gw[f][e]

__global__ __launch_bounds__(256) void prep_kernel(
    const float* __restrict__ masker, const float* __restrict__ ln_w,
    const float* __restrict__ ln_b, const float* __restrict__ tw,
    const float* __restrict__ tb, const float* __restrict__ gw,
    bf16_t* __restrict__ ws_attnT, bf16_t* __restrict__ ws_WT,
    float* __restrict__ ws_tbT, float* __restrict__ ws_gwT,
    float* __restrict__ ws_cst)
{
  __shared__ float red[2][4];
  const int tid = threadIdx.x;
  const int lane = tid & 63;
  const int gidx = blockIdx.x * 256 + tid;   // 0..4095

  // ---- WT staging: 16384 elems, 4/thread ----
#pragma unroll
  for (int j = 0; j < 4; ++j) {
    int o = gidx * 4 + j;            // ((t*2+i)*64 + e)*64 + k
    int k = o & 63;
    int e = (o >> 6) & 63;
    int ti = o >> 12;                // t*2+i
    ws_WT[o] = (bf16_t)tw[(ti * 64 + k) * 64 + e];
  }

  // ---- tbT staging: 8192 elems, 2/thread ----
#pragma unroll
  for (int j = 0; j < 2; ++j) {
    int o = gidx * 2 + j;            // (t*64 + e)*64 + f
    int f = o & 63;
    int e = (o >> 6) & 63;
    int t = o >> 12;
    ws_tbT[o] = (f < NFEAT) ? tb[(t * NFEAT + f) * EDIM + e] : 0.f;
  }

  // ---- gwT staging: 4096 elems, 1/thread ----
  {
    int o = gidx;                    // e*64 + f
    int f = o & 63;
    int e = o >> 6;
    ws_gwT[o] = (f < NFEAT) ? gw[f * EDIM + e] : 0.f;
  }

  // ---- gate-bias constants: cst[t] = sum tb_t * gw (block 0 only) ----
  if (blockIdx.x == 0) {
    float s0 = 0.f, s1 = 0.f;
    for (int i = tid; i < NFEAT * EDIM; i += 256) {
      float g = gw[i];
      s0 += tb[i] * g;
      s1 += tb[NFEAT * EDIM + i] * g;
    }
    for (int off = 32; off > 0; off >>= 1) {
      s0 += __shfl_xor(s0, off);
      s1 += __shfl_xor(s1, off);
    }
    if (lane == 0) { red[0][tid >> 6] = s0; red[1][tid >> 6] = s1; }
    __syncthreads();
    if (tid == 0) {
      ws_cst[0] = red[0][0] + red[0][1] + red[0][2] + red[0][3];
      ws_cst[1] = red[1][0] + red[1][1] + red[1][2] + red[1][3];
    }
  }

  // ---- attention columns: 128 tasks (t,g) over 64 waves, 2 each ----
  const int wg = blockIdx.x * 4 + (tid >> 6);  // 0..63
  const int f = lane;
  const bool fv = (f < NFEAT);
  for (int i = 0; i < 2; ++i) {
    int col = wg * 2 + i;            // 0..127
    int t = col >> 6, g = col & 63;
    float val = 0.f;
    if (fv && g < NFEAT) {
      float a0 = masker[((t * 3 + 0) * NFEAT + f) * NFEAT + g];
      float a1 = masker[((t * 3 + 1) * NFEAT + f) * NFEAT + g];
      float a2 = masker[((t * 3 + 2) * NFEAT + f) * NFEAT + g];
      float prod = a0 * a1 * a2;
      val = prod > 0.f ? prod : 0.f;            // relu
    }
    float s = val;
    for (int off = 32; off > 0; off >>= 1) s += __shfl_xor(s, off);
    float mean = s / (float)NFEAT;
    float d = fv ? (val - mean) : 0.f;
    float v2 = d * d;
    for (int off = 32; off > 0; off >>= 1) v2 += __shfl_xor(v2, off);
    float var = v2 / (float)NFEAT;
    float lw = fv ? ln_w[f] : 0.f;
    float lb = fv ? ln_b[f] : 0.f;
    float aln = d * rsqrtf(var + LN_EPS) * lw + lb;
    float logit = aln + ((val != 0.f) ? 0.f : NEG_INF_C) + ((f == g) ? 1.f : 0.f);
    if (!fv) logit = -3.0e38f;
    float mx = logit;
    for (int off = 32; off > 0; off >>= 1) mx = fmaxf(mx, __shfl_xor(mx, off));
    float ex = fv ? expf(logit - mx) : 0.f;
    float se = ex;
    for (int off = 32; off > 0; off >>= 1) se += __shfl_xor(se, off);
    float attn = (fv && g < NFEAT && val != 0.f) ? (ex / se) : 0.f;
    ws_attnT[(t * 64 + g) * 64 + f] = (bf16_t)attn;
  }
}

// One block = ONE batch. 4 waves; wave w owns rows 16w..16w+15.
// No launch_bounds cap (round-1 lesson: forcing VGPR<=128 spills accumulators
// -> 320 MB scratch traffic). Instead: 4096 small blocks so the CU always has
// fresh independent blocks to overlap with barrier/latency stalls.
// All non-accumulator operands (aat/gw/tb) are loaded transiently at first use
// to keep peak pressure = accumulators + in-flight B-frags.
__global__ __launch_bounds__(256) void main_kernel(
    const float* __restrict__ feat, const float* __restrict__ gb,
    const bf16_t* __restrict__ ws_attnT, const bf16_t* __restrict__ ws_WT,
    const float* __restrict__ ws_tbT, const float* __restrict__ ws_gwT,
    const float* __restrict__ ws_cst,
    float* __restrict__ out)
{
  __shared__ bf16_t sPT[2][64 * 72];   // P^T[e][f'] per t, pitch 72
  __shared__ float sLog[2][4];

  const int tid = threadIdx.x;
  const int w = tid >> 6;
  const int lane = tid & 63;
  const int l16 = lane & 15;
  const int lquad = lane >> 4;
  const int m0 = w * 16;

  const int b = blockIdx.x;
  const float* featb = feat + b * (NFEAT * EDIM);
  const int fA = m0 + l16;
  const bool fAv = (fA < NFEAT);

  // ---- feat A-frags (the long-latency load; issue first) ----
  bf16x8 a[2];
#pragma unroll
  for (int kc = 0; kc < 2; ++kc)
#pragma unroll
    for (int j = 0; j < 8; ++j) a[kc][j] = (bf16_t)0.f;
  if (fAv) {
    const float* fb = featb + fA * 64 + lquad * 8;
    f32x4 r0 = *(const f32x4*)(fb);
    f32x4 r1 = *(const f32x4*)(fb + 4);
    f32x4 r2 = *(const f32x4*)(fb + 32);
    f32x4 r3 = *(const f32x4*)(fb + 36);
#pragma unroll
    for (int j = 0; j < 4; ++j) {
      a[0][j] = (bf16_t)r0[j]; a[0][j + 4] = (bf16_t)r1[j];
      a[1][j] = (bf16_t)r2[j]; a[1][j + 4] = (bf16_t)r3[j];
    }
  }

  f32x4 accH[2][4], accP[2][4];
#pragma unroll
  for (int t = 0; t < 2; ++t)
#pragma unroll
    for (int n = 0; n < 4; ++n) {
      accH[t][n] = (f32x4){0.f, 0.f, 0.f, 0.f};
      accP[t][n] = (f32x4){0.f, 0.f, 0.f, 0.f};
    }

  // ---- pass 1: accH[t] = F@W1_t, accP[t] = F@W2_t (4 independent streams) ----
#pragma unroll
  for (int kc = 0; kc < 2; ++kc) {
#pragma unroll
    for (int n = 0; n < 4; ++n) {
      const int bo = (n * 16 + l16) * 64 + kc * 32 + lquad * 8;
      const bf16x8 b10 = *(const bf16x8*)(ws_WT + (0 * 64) * 64 + bo);  // t0 W1
      const bf16x8 b20 = *(const bf16x8*)(ws_WT + (1 * 64) * 64 + bo);  // t0 W2
      const bf16x8 b11 = *(const bf16x8*)(ws_WT + (2 * 64) * 64 + bo);  // t1 W1
      const bf16x8 b21 = *(const bf16x8*)(ws_WT + (3 * 64) * 64 + bo);  // t1 W2
      accH[0][n] = __builtin_amdgcn_mfma_f32_16x16x32_bf16(a[kc], b10, accH[0][n], 0, 0, 0);
      accP[0][n] = __builtin_amdgcn_mfma_f32_16x16x32_bf16(a[kc], b20, accP[0][n], 0, 0, 0);
      accH[1][n] = __builtin_amdgcn_mfma_f32_16x16x32_bf16(a[kc], b11, accH[1][n], 0, 0, 0);
      accP[1][n] = __builtin_amdgcn_mfma_f32_16x16x32_bf16(a[kc], b21, accP[1][n], 0, 0, 0);
    }
  }

  // ---- write both P^T tiles to LDS ----
#pragma unroll
  for (int t = 0; t < 2; ++t)
#pragma unroll
    for (int n = 0; n < 4; ++n) {
      bf16x4 pv;
      pv[0] = (bf16_t)accP[t][n][0]; pv[1] = (bf16_t)accP[t][n][1];
      pv[2] = (bf16_t)accP[t][n][2]; pv[3] = (bf16_t)accP[t][n][3];
      *(bf16x4*)&sPT[t][(n * 16 + l16) * 72 + m0 + lquad * 4] = pv;
    }
  __syncthreads();

  // ---- pass 2: accH[t] += attnT_t @ P_t (aat loaded here, L2-hot) ----
#pragma unroll
  for (int kc = 0; kc < 2; ++kc) {
    const bf16x8 aat0 = *(const bf16x8*)(ws_attnT + (0 * 64 + m0 + l16) * 64 + kc * 32 + lquad * 8);
    const bf16x8 aat1 = *(const bf16x8*)(ws_attnT + (1 * 64 + m0 + l16) * 64 + kc * 32 + lquad * 8);
#pragma unroll
    for (int n = 0; n < 4; ++n) {
      const int so = (n * 16 + l16) * 72 + kc * 32 + lquad * 8;
      const bf16x8 bp0 = *(const bf16x8*)(&sPT[0][so]);
      const bf16x8 bp1 = *(const bf16x8*)(&sPT[1][so]);
      accH[0][n] = __builtin_amdgcn_mfma_f32_16x16x32_bf16(aat0, bp0, accH[0][n], 0, 0, 0);
      accH[1][n] = __builtin_amdgcn_mfma_f32_16x16x32_bf16(aat1, bp1, accH[1][n], 0, 0, 0);
    }
  }

  // ---- gate-logit partials: p_t = sum accH_t * gw (tb bias folded into cst) ----
  float p0 = 0.f, p1 = 0.f;
#pragma unroll
  for (int n = 0; n < 4; ++n) {
    const f32x4 gwv = *(const f32x4*)(ws_gwT + (n * 16 + l16) * 64 + m0 + lquad * 4);
#pragma unroll
    for (int r = 0; r < 4; ++r) {
      p0 += accH[0][n][r] * gwv[r];
      p1 += accH[1][n][r] * gwv[r];
    }
  }
#pragma unroll
  for (int off = 32; off > 0; off >>= 1) {
    p0 += __shfl_xor(p0, off);
    p1 += __shfl_xor(p1, off);
  }
  if (lane == 0) { sLog[0][w] = p0; sLog[1][w] = p1; }
  __syncthreads();

  // ---- gate softmax over T=2, weighted sum (+tb at store time), store ----
  const float g0 = sLog[0][0] + sLog[0][1] + sLog[0][2] + sLog[0][3] + ws_cst[0] + gb[0];
  const float g1 = sLog[1][0] + sLog[1][1] + sLog[1][2] + sLog[1][3] + ws_cst[1] + gb[0];
  const float mx = fmaxf(g0, g1);
  const float e0 = expf(g0 - mx), e1 = expf(g1 - mx);
  const float inv = 1.f / (e0 + e1);
  const float ga0 = e0 * inv, ga1 = e1 * inv;

  float* outb = out + b * (NFEAT * EDIM);
#pragma unroll
  for (int n = 0; n < 4; ++n) {
    const int ro = (n * 16 + l16) * 64 + m0 + lquad * 4;
    const f32x4 tbv0 = *(const f32x4*)(ws_tbT + ro);
    const f32x4 tbv1 = *(const f32x4*)(ws_tbT + 64 * 64 + ro);
    int e = n * 16 + l16;
#pragma unroll
    for (int r = 0; r < 4; ++r) {
      int f = m0 + lquad * 4 + r;
      if (f < NFEAT)
        outb[f * 64 + e] = ga0 * (accH[0][n][r] + tbv0[r])
                         + ga1 * (accH[1][n][r] + tbv1[r]);
    }
  }
}

extern "C" void kernel_launch(void* const* d_in, const int* in_sizes, int n_in,
                              void* d_out, int out_size, void* d_ws, size_t ws_size,
                              hipStream_t stream) {
  const float* feat   = (const float*)d_in[0];
  const float* masker = (const float*)d_in[1];
  const float* tw     = (const float*)d_in[2];
  const float* tb     = (const float*)d_in[3];
  const float* lnw    = (const float*)d_in[4];
  const float* lnb    = (const float*)d_in[5];
  const float* gw     = (const float*)d_in[6];
  const float* gb     = (const float*)d_in[7];
  float* out = (float*)d_out;

  bf16_t* ws_attnT = (bf16_t*)d_ws;                 // 8192 bf16
  bf16_t* ws_WT    = ws_attnT + 2 * 64 * 64;        // 16384 bf16
  float*  ws_tbT   = (float*)(ws_WT + 4 * 64 * 64); // 8192 f32
  float*  ws_gwT   = ws_tbT + 2 * 64 * 64;          // 4096 f32
  float*  ws_cst   = ws_gwT + 64 * 64;              // 2 f32

  prep_kernel<<<16, 256, 0, stream>>>(masker, lnw, lnb, tw, tb, gw,
                                      ws_attnT, ws_WT, ws_tbT, ws_gwT, ws_cst);
  main_kernel<<<4096, 256, 0, stream>>>(feat, gb, ws_attnT, ws_WT,
                                        ws_tbT, ws_gwT, ws_cst, out);
}